// Round 3
// baseline (2281.236 us; speedup 1.0000x reference)
//
#include <hip/hip_runtime.h>

#define N_NODES 50000
#define N_EDGES 1600000
#define HC 128        // H*C == IN
#define LAYERS 3
#define NGRAPH 64
#define OUT_CH 64

// ---------------- zero helpers ----------------
__global__ void zero_f32(float* __restrict__ p, long n) {
    long i = (long)blockIdx.x * blockDim.x + threadIdx.x;
    long stride = (long)gridDim.x * blockDim.x;
    for (; i < n; i += stride) p[i] = 0.f;
}
__global__ void zero_i32(int* __restrict__ p, int n) {
    int i = blockIdx.x * blockDim.x + threadIdx.x;
    int stride = gridDim.x * blockDim.x;
    for (; i < n; i += stride) p[i] = 0;
}

// ---------------- CSR build: histogram -> scan -> scatter ----------------
__global__ void hist_dst(const int* __restrict__ ei, int* __restrict__ cnt) {
    int e = blockIdx.x * blockDim.x + threadIdx.x;
    if (e < N_EDGES) atomicAdd(&cnt[ei[N_EDGES + e]], 1);
}

#define SCAN_T 1024
__global__ __launch_bounds__(SCAN_T) void scan_rowptr(
    const int* __restrict__ cnt, int* __restrict__ rowptr)
{
    __shared__ int part[SCAN_T];
    const int t = threadIdx.x;
    const int CHK = (N_NODES + SCAN_T - 1) / SCAN_T;   // 49
    const int base = t * CHK;
    int s = 0;
    for (int i = 0; i < CHK; ++i) {
        int idx = base + i;
        if (idx < N_NODES) s += cnt[idx];
    }
    part[t] = s;
    __syncthreads();
    // Hillis-Steele inclusive scan (read-all then write-all per round)
    for (int off = 1; off < SCAN_T; off <<= 1) {
        int add = (t >= off) ? part[t - off] : 0;
        __syncthreads();
        part[t] += add;
        __syncthreads();
    }
    int run = part[t] - s;   // exclusive prefix of this thread's chunk
    for (int i = 0; i < CHK; ++i) {
        int idx = base + i;
        if (idx < N_NODES) {
            rowptr[idx] = run;
            run += cnt[idx];
        }
    }
    if (t == SCAN_T - 1) rowptr[N_NODES] = part[t];
}

__global__ void scatter_edges(const int* __restrict__ ei,
                              const int* __restrict__ rowptr,
                              int* __restrict__ fill,
                              int* __restrict__ esrc, int* __restrict__ edst)
{
    int e = blockIdx.x * blockDim.x + threadIdx.x;
    if (e < N_EDGES) {
        int d = ei[N_EDGES + e];
        int pos = rowptr[d] + atomicAdd(&fill[d], 1);
        esrc[pos] = ei[e];
        edst[pos] = d;
    }
}

// ---------------- fused 4-matrix GEMM: out_m = x @ W_m + b_m ----------------
// x [N,128], W [128,128] row-major, out [N,128]. 64 rows/block, 256 thr,
// each thread 4 rows x 8 cols per matrix.
__global__ __launch_bounds__(256) void gemm4(
    const float* __restrict__ x,
    const float* __restrict__ Wq, const float* __restrict__ bq,
    const float* __restrict__ Wk, const float* __restrict__ bk,
    const float* __restrict__ Wv, const float* __restrict__ bv,
    const float* __restrict__ Wsk, const float* __restrict__ bsk,
    float* __restrict__ oq, float* __restrict__ ok_,
    float* __restrict__ ov, float* __restrict__ osk)
{
    __shared__ float xs[64][132];   // +4 pad keeps float4 align, breaks bank stride
    const int bRow = blockIdx.x * 64;
    const int tid = threadIdx.x;

    for (int i = tid; i < 64 * 32; i += 256) {
        int r = i >> 5, c4 = i & 31;
        int gr = bRow + r;
        float4 val = make_float4(0.f, 0.f, 0.f, 0.f);
        if (gr < N_NODES)
            val = *reinterpret_cast<const float4*>(x + (long)gr * HC + c4 * 4);
        *reinterpret_cast<float4*>(&xs[r][c4 * 4]) = val;
    }
    __syncthreads();

    const int rg = tid >> 4;   // 0..15 -> rows rg*4 .. rg*4+3
    const int cg = tid & 15;   // 0..15 -> cols cg*8 .. cg*8+7

    const float* Wm[4] = {Wq, Wk, Wv, Wsk};
    const float* bm[4] = {bq, bk, bv, bsk};
    float* om[4] = {oq, ok_, ov, osk};

    #pragma unroll
    for (int m = 0; m < 4; ++m) {
        const float* __restrict__ W = Wm[m];
        const float* __restrict__ b = bm[m];
        float acc[4][8];
        #pragma unroll
        for (int i = 0; i < 4; ++i)
            #pragma unroll
            for (int j = 0; j < 8; ++j) acc[i][j] = b[cg * 8 + j];

        for (int kk = 0; kk < 128; ++kk) {
            float4 w0 = *reinterpret_cast<const float4*>(W + kk * HC + cg * 8);
            float4 w1 = *reinterpret_cast<const float4*>(W + kk * HC + cg * 8 + 4);
            float wv[8] = {w0.x, w0.y, w0.z, w0.w, w1.x, w1.y, w1.z, w1.w};
            #pragma unroll
            for (int i = 0; i < 4; ++i) {
                float xv = xs[rg * 4 + i][kk];
                #pragma unroll
                for (int j = 0; j < 8; ++j) acc[i][j] += xv * wv[j];
            }
        }
        float* __restrict__ o = om[m];
        #pragma unroll
        for (int i = 0; i < 4; ++i) {
            int gr = bRow + rg * 4 + i;
            if (gr < N_NODES) {
                *reinterpret_cast<float4*>(o + (long)gr * HC + cg * 8) =
                    make_float4(acc[i][0], acc[i][1], acc[i][2], acc[i][3]);
                *reinterpret_cast<float4*>(o + (long)gr * HC + cg * 8 + 4) =
                    make_float4(acc[i][4], acc[i][5], acc[i][6], acc[i][7]);
            }
        }
    }
}

// ---------------- edge logits (sorted order): p = exp(q[dst].k[src]*scale) ----
// lane = (edge_in_wave<<2)|head; 16 edges per wave64; private 32-FMA dot,
// no shuffles, no atomics. Write is wave-coalesced (index = wave*64+lane).
__global__ __launch_bounds__(256) void edge_logits_sorted(
    const float* __restrict__ q, const float* __restrict__ k,
    const int* __restrict__ esrc, const int* __restrict__ edst,
    float* __restrict__ p)
{
    const int lane = threadIdx.x & 63;
    const long wave = ((long)blockIdx.x * blockDim.x + threadIdx.x) >> 6;
    const int eloc = lane >> 2;      // 0..15
    const int h = lane & 3;          // head
    const long pos = wave * 16 + eloc;
    if (pos >= N_EDGES) return;
    const int s = esrc[pos];
    const int d = edst[pos];
    const float4* kr = reinterpret_cast<const float4*>(k + (long)s * HC + h * 32);
    const float4* qr = reinterpret_cast<const float4*>(q + (long)d * HC + h * 32);
    float acc = 0.f;
    #pragma unroll
    for (int i = 0; i < 8; ++i) {
        float4 a = qr[i], b = kr[i];
        acc += a.x * b.x + a.y * b.y + a.z * b.z + a.w * b.w;
    }
    p[pos * 4 + h] = __expf(acc * 0.17677669529663687f);  // 1/sqrt(32)
}

// ---------------- node-centric aggregate + skip + relu -------------------
// one wave per dst node; lane covers channels (lane, lane+64).
// agg = (sum_e p*v) / (sum_e p); x = relu(agg + skip). No atomics.
__global__ __launch_bounds__(256) void node_aggregate(
    const float* __restrict__ v, const float* __restrict__ p,
    const float* __restrict__ skip,
    const int* __restrict__ rowptr, const int* __restrict__ esrc,
    float* __restrict__ xout)
{
    const int lane = threadIdx.x & 63;
    const int node = (int)(((long)blockIdx.x * blockDim.x + threadIdx.x) >> 6);
    if (node >= N_NODES) return;
    const int beg = rowptr[node], end = rowptr[node + 1];
    const int c0 = lane, c1 = lane + 64;
    const int h0 = lane >> 5;        // head of c0 (0/1); head of c1 is h0+2
    float acc0 = 0.f, acc1 = 0.f, ps0 = 0.f, ps1 = 0.f;
    for (int pos = beg; pos < end; ++pos) {
        const int s = esrc[pos];
        const float* vr = v + (long)s * HC;
        const float* pp = p + (long)pos * 4;
        float p0 = pp[h0];
        float p1 = pp[h0 + 2];
        acc0 += p0 * vr[c0];
        acc1 += p1 * vr[c1];
        ps0 += p0;
        ps1 += p1;
    }
    const long b = (long)node * HC;
    float r0 = acc0 / (ps0 + 1e-16f) + skip[b + c0];
    float r1 = acc1 / (ps1 + 1e-16f) + skip[b + c1];
    xout[b + c0] = r0 > 0.f ? r0 : 0.f;
    xout[b + c1] = r1 > 0.f ? r1 : 0.f;
}

// ---------------- global mean pool (atomic) ----------------
__global__ void pool_sum(const float* __restrict__ x, const int* __restrict__ batch,
                         float* __restrict__ gsum, float* __restrict__ gcnt)
{
    long i = (long)blockIdx.x * blockDim.x + threadIdx.x;
    if (i < (long)N_NODES * HC) {
        int n = (int)(i >> 7);
        int c = (int)(i & 127);
        int g = batch[n];
        atomicAdd(&gsum[g * HC + c], x[i]);
        if (c == 0) atomicAdd(&gcnt[g], 1.0f);
    }
}

// ---------------- final FC: out = (gsum/max(cnt,1)) @ fcW + fcb ----------------
__global__ void final_fc(const float* __restrict__ gsum, const float* __restrict__ gcnt,
                         const float* __restrict__ fcW, const float* __restrict__ fcb,
                         float* __restrict__ out)
{
    int i = blockIdx.x * blockDim.x + threadIdx.x;
    if (i < NGRAPH * OUT_CH) {
        int g = i >> 6, o = i & 63;
        float cnt = gcnt[g];
        cnt = cnt > 1.f ? cnt : 1.f;
        float inv = 1.f / cnt;
        float accv = fcb[o];
        for (int c = 0; c < HC; ++c)
            accv += (gsum[g * HC + c] * inv) * fcW[c * OUT_CH + o];
        out[i] = accv;
    }
}

extern "C" void kernel_launch(void* const* d_in, const int* in_sizes, int n_in,
                              void* d_out, int out_size, void* d_ws, size_t ws_size,
                              hipStream_t stream)
{
    const float* x0   = (const float*)d_in[0];
    const int*   ei   = (const int*)d_in[1];
    const int*   batch= (const int*)d_in[2];
    const float* Wq   = (const float*)d_in[3];
    const float* bq   = (const float*)d_in[4];
    const float* Wk   = (const float*)d_in[5];
    const float* bk   = (const float*)d_in[6];
    const float* Wv   = (const float*)d_in[7];
    const float* bv   = (const float*)d_in[8];
    const float* Wsk  = (const float*)d_in[9];
    const float* bsk  = (const float*)d_in[10];
    const float* fcW  = (const float*)d_in[11];
    const float* fcb  = (const float*)d_in[12];
    float* out = (float*)d_out;

    const long NH = (long)N_NODES * HC;   // 6.4M floats
    float* ws   = (float*)d_ws;
    float* q    = ws;                    // NH
    float* k    = q + NH;                // NH
    float* v    = k + NH;                // NH
    float* skip = v + NH;                // NH
    float* xA   = skip + NH;             // NH
    float* p    = xA + NH;               // E*4
    float* gsum = p + (long)N_EDGES * 4; // G*HC
    float* gcnt = gsum + NGRAPH * HC;    // G
    int*   iws  = (int*)(gcnt + NGRAPH);
    int*   rowptr = iws;                 // N+1
    int*   cnt    = rowptr + (N_NODES + 1);  // N (reused as fill)
    int*   esrc   = cnt + N_NODES;       // E
    int*   edst   = esrc + N_EDGES;      // E

    const int gemmGrid = (N_NODES + 63) / 64;                     // 782
    const int eGrid    = (N_EDGES + 255) / 256;                   // 6250
    const int logitGrid = (int)(((long)N_EDGES * 4 + 255) / 256); // 25000 (16 edges/wave)
    const int nodeGrid = (N_NODES + 3) / 4;                       // 12500 (4 waves/block)
    const int elemGrid = (int)((NH + 255) / 256);                 // 25000

    // ---- CSR build (once per launch; edge_index is layer-invariant) ----
    zero_i32<<<256, 256, 0, stream>>>(cnt, N_NODES);
    hist_dst<<<eGrid, 256, 0, stream>>>(ei, cnt);
    scan_rowptr<<<1, SCAN_T, 0, stream>>>(cnt, rowptr);
    zero_i32<<<256, 256, 0, stream>>>(cnt, N_NODES);   // reuse as fill
    scatter_edges<<<eGrid, 256, 0, stream>>>(ei, rowptr, cnt, esrc, edst);

    // ---- layers ----
    const float* xin = x0;
    for (int l = 0; l < LAYERS; ++l) {
        const long wOff = (long)l * HC * HC;
        const long bOff = (long)l * HC;
        gemm4<<<gemmGrid, 256, 0, stream>>>(xin,
            Wq + wOff, bq + bOff, Wk + wOff, bk + bOff,
            Wv + wOff, bv + bOff, Wsk + wOff, bsk + bOff,
            q, k, v, skip);
        edge_logits_sorted<<<logitGrid, 256, 0, stream>>>(q, k, esrc, edst, p);
        node_aggregate<<<nodeGrid, 256, 0, stream>>>(v, p, skip, rowptr, esrc, xA);
        xin = xA;
    }

    // ---- pooling + fc ----
    zero_f32<<<64, 256, 0, stream>>>(gsum, (long)NGRAPH * HC + NGRAPH);
    pool_sum<<<elemGrid, 256, 0, stream>>>(xin, batch, gsum, gcnt);
    final_fc<<<(NGRAPH * OUT_CH + 255) / 256, 256, 0, stream>>>(gsum, gcnt, fcW, fcb, out);
}

// Round 4
// 1894.901 us; speedup vs baseline: 1.2039x; 1.2039x over previous
//
#include <hip/hip_runtime.h>

#define N_NODES 50000
#define N_EDGES 1600000
#define HC 128        // H*C == IN
#define LAYERS 3
#define NGRAPH 64
#define OUT_CH 64

// ---------------- zero helpers ----------------
__global__ void zero_f32(float* __restrict__ p, long n) {
    long i = (long)blockIdx.x * blockDim.x + threadIdx.x;
    long stride = (long)gridDim.x * blockDim.x;
    for (; i < n; i += stride) p[i] = 0.f;
}
__global__ void zero_i32(int* __restrict__ p, int n) {
    int i = blockIdx.x * blockDim.x + threadIdx.x;
    int stride = gridDim.x * blockDim.x;
    for (; i < n; i += stride) p[i] = 0;
}

// ---------------- CSR build: histogram -> scan -> scatter ----------------
__global__ void hist_dst(const int* __restrict__ ei, int* __restrict__ cnt) {
    int e = blockIdx.x * blockDim.x + threadIdx.x;
    if (e < N_EDGES) atomicAdd(&cnt[ei[N_EDGES + e]], 1);
}

#define SCAN_T 1024
__global__ __launch_bounds__(SCAN_T) void scan_rowptr(
    const int* __restrict__ cnt, int* __restrict__ rowptr)
{
    __shared__ int part[SCAN_T];
    const int t = threadIdx.x;
    const int CHK = (N_NODES + SCAN_T - 1) / SCAN_T;   // 49
    const int base = t * CHK;
    int s = 0;
    for (int i = 0; i < CHK; ++i) {
        int idx = base + i;
        if (idx < N_NODES) s += cnt[idx];
    }
    part[t] = s;
    __syncthreads();
    // Hillis-Steele inclusive scan (read-all then write-all per round)
    for (int off = 1; off < SCAN_T; off <<= 1) {
        int add = (t >= off) ? part[t - off] : 0;
        __syncthreads();
        part[t] += add;
        __syncthreads();
    }
    int run = part[t] - s;   // exclusive prefix of this thread's chunk
    for (int i = 0; i < CHK; ++i) {
        int idx = base + i;
        if (idx < N_NODES) {
            rowptr[idx] = run;
            run += cnt[idx];
        }
    }
    if (t == SCAN_T - 1) rowptr[N_NODES] = part[t];
}

__global__ void scatter_edges(const int* __restrict__ ei,
                              const int* __restrict__ rowptr,
                              int* __restrict__ fill,
                              int* __restrict__ esrc, int* __restrict__ edst)
{
    int e = blockIdx.x * blockDim.x + threadIdx.x;
    if (e < N_EDGES) {
        int d = ei[N_EDGES + e];
        int pos = rowptr[d] + atomicAdd(&fill[d], 1);
        esrc[pos] = ei[e];
        edst[pos] = d;
    }
}

// ---------------- fused 4-matrix GEMM: out_m = x @ W_m + b_m ----------------
__global__ __launch_bounds__(256) void gemm4(
    const float* __restrict__ x,
    const float* __restrict__ Wq, const float* __restrict__ bq,
    const float* __restrict__ Wk, const float* __restrict__ bk,
    const float* __restrict__ Wv, const float* __restrict__ bv,
    const float* __restrict__ Wsk, const float* __restrict__ bsk,
    float* __restrict__ oq, float* __restrict__ ok_,
    float* __restrict__ ov, float* __restrict__ osk)
{
    __shared__ float xs[64][132];   // +4 pad keeps float4 align, breaks bank stride
    const int bRow = blockIdx.x * 64;
    const int tid = threadIdx.x;

    for (int i = tid; i < 64 * 32; i += 256) {
        int r = i >> 5, c4 = i & 31;
        int gr = bRow + r;
        float4 val = make_float4(0.f, 0.f, 0.f, 0.f);
        if (gr < N_NODES)
            val = *reinterpret_cast<const float4*>(x + (long)gr * HC + c4 * 4);
        *reinterpret_cast<float4*>(&xs[r][c4 * 4]) = val;
    }
    __syncthreads();

    const int rg = tid >> 4;   // 0..15 -> rows rg*4 .. rg*4+3
    const int cg = tid & 15;   // 0..15 -> cols cg*8 .. cg*8+7

    const float* Wm[4] = {Wq, Wk, Wv, Wsk};
    const float* bm[4] = {bq, bk, bv, bsk};
    float* om[4] = {oq, ok_, ov, osk};

    #pragma unroll
    for (int m = 0; m < 4; ++m) {
        const float* __restrict__ W = Wm[m];
        const float* __restrict__ b = bm[m];
        float acc[4][8];
        #pragma unroll
        for (int i = 0; i < 4; ++i)
            #pragma unroll
            for (int j = 0; j < 8; ++j) acc[i][j] = b[cg * 8 + j];

        for (int kk = 0; kk < 128; ++kk) {
            float4 w0 = *reinterpret_cast<const float4*>(W + kk * HC + cg * 8);
            float4 w1 = *reinterpret_cast<const float4*>(W + kk * HC + cg * 8 + 4);
            float wv[8] = {w0.x, w0.y, w0.z, w0.w, w1.x, w1.y, w1.z, w1.w};
            #pragma unroll
            for (int i = 0; i < 4; ++i) {
                float xv = xs[rg * 4 + i][kk];
                #pragma unroll
                for (int j = 0; j < 8; ++j) acc[i][j] += xv * wv[j];
            }
        }
        float* __restrict__ o = om[m];
        #pragma unroll
        for (int i = 0; i < 4; ++i) {
            int gr = bRow + rg * 4 + i;
            if (gr < N_NODES) {
                *reinterpret_cast<float4*>(o + (long)gr * HC + cg * 8) =
                    make_float4(acc[i][0], acc[i][1], acc[i][2], acc[i][3]);
                *reinterpret_cast<float4*>(o + (long)gr * HC + cg * 8 + 4) =
                    make_float4(acc[i][4], acc[i][5], acc[i][6], acc[i][7]);
            }
        }
    }
}

// ---------------- edge logits (sorted order): p = exp(q[dst].k[src]*scale) ----
__global__ __launch_bounds__(256) void edge_logits_sorted(
    const float* __restrict__ q, const float* __restrict__ k,
    const int* __restrict__ esrc, const int* __restrict__ edst,
    float* __restrict__ p)
{
    const int lane = threadIdx.x & 63;
    const long wave = ((long)blockIdx.x * blockDim.x + threadIdx.x) >> 6;
    const int eloc = lane >> 2;      // 0..15
    const int h = lane & 3;          // head
    const long pos = wave * 16 + eloc;
    if (pos >= N_EDGES) return;
    const int s = esrc[pos];
    const int d = edst[pos];
    const float4* kr = reinterpret_cast<const float4*>(k + (long)s * HC + h * 32);
    const float4* qr = reinterpret_cast<const float4*>(q + (long)d * HC + h * 32);
    float acc = 0.f;
    #pragma unroll
    for (int i = 0; i < 8; ++i) {
        float4 a = qr[i], b = kr[i];
        acc += a.x * b.x + a.y * b.y + a.z * b.z + a.w * b.w;
    }
    p[pos * 4 + h] = __expf(acc * 0.17677669529663687f);  // 1/sqrt(32)
}

// ---------------- node-centric aggregate + skip + relu -------------------
__global__ __launch_bounds__(256) void node_aggregate(
    const float* __restrict__ v, const float* __restrict__ p,
    const float* __restrict__ skip,
    const int* __restrict__ rowptr, const int* __restrict__ esrc,
    float* __restrict__ xout)
{
    const int lane = threadIdx.x & 63;
    const int node = (int)(((long)blockIdx.x * blockDim.x + threadIdx.x) >> 6);
    if (node >= N_NODES) return;
    const int beg = rowptr[node], end = rowptr[node + 1];
    const int c0 = lane, c1 = lane + 64;
    const int h0 = lane >> 5;        // head of c0 (0/1); head of c1 is h0+2
    float acc0 = 0.f, acc1 = 0.f, ps0 = 0.f, ps1 = 0.f;
    for (int pos = beg; pos < end; ++pos) {
        const int s = esrc[pos];
        const float* vr = v + (long)s * HC;
        const float* pp = p + (long)pos * 4;
        float p0 = pp[h0];
        float p1 = pp[h0 + 2];
        acc0 += p0 * vr[c0];
        acc1 += p1 * vr[c1];
        ps0 += p0;
        ps1 += p1;
    }
    const long b = (long)node * HC;
    float r0 = acc0 / (ps0 + 1e-16f) + skip[b + c0];
    float r1 = acc1 / (ps1 + 1e-16f) + skip[b + c1];
    xout[b + c0] = r0 > 0.f ? r0 : 0.f;
    xout[b + c1] = r1 > 0.f ? r1 : 0.f;
}

// ---------------- global mean pool: chunked run-length reduction ---------
// batch is sorted => each graph is a contiguous node run. Each 128-thread
// block accumulates 64 consecutive nodes per channel in registers and
// flushes one atomicAdd per (graph-run, channel): ~110K atomics vs 6.4M.
#define POOL_CHUNK 64
__global__ __launch_bounds__(128) void pool_sum2(
    const float* __restrict__ x, const int* __restrict__ batch,
    float* __restrict__ gsum, float* __restrict__ gcnt)
{
    const int c = threadIdx.x;            // 0..127 (channel)
    const int base = blockIdx.x * POOL_CHUNK;
    if (base >= N_NODES) return;
    const int end = min(base + POOL_CHUNK, N_NODES);
    float acc = 0.f;
    int cnt = 0;
    int curg = batch[base];
    for (int n = base; n < end; ++n) {
        int g = batch[n];
        if (g != curg) {
            atomicAdd(&gsum[curg * HC + c], acc);
            if (c == 0) atomicAdd(&gcnt[curg], (float)cnt);
            acc = 0.f; cnt = 0; curg = g;
        }
        acc += x[(long)n * HC + c];
        cnt++;
    }
    atomicAdd(&gsum[curg * HC + c], acc);
    if (c == 0) atomicAdd(&gcnt[curg], (float)cnt);
}

// ---------------- final FC: out = (gsum/max(cnt,1)) @ fcW + fcb ----------------
__global__ void final_fc(const float* __restrict__ gsum, const float* __restrict__ gcnt,
                         const float* __restrict__ fcW, const float* __restrict__ fcb,
                         float* __restrict__ out)
{
    int i = blockIdx.x * blockDim.x + threadIdx.x;
    if (i < NGRAPH * OUT_CH) {
        int g = i >> 6, o = i & 63;
        float cnt = gcnt[g];
        cnt = cnt > 1.f ? cnt : 1.f;
        float inv = 1.f / cnt;
        float accv = fcb[o];
        for (int c = 0; c < HC; ++c)
            accv += (gsum[g * HC + c] * inv) * fcW[c * OUT_CH + o];
        out[i] = accv;
    }
}

extern "C" void kernel_launch(void* const* d_in, const int* in_sizes, int n_in,
                              void* d_out, int out_size, void* d_ws, size_t ws_size,
                              hipStream_t stream)
{
    const float* x0   = (const float*)d_in[0];
    const int*   ei   = (const int*)d_in[1];
    const int*   batch= (const int*)d_in[2];
    const float* Wq   = (const float*)d_in[3];
    const float* bq   = (const float*)d_in[4];
    const float* Wk   = (const float*)d_in[5];
    const float* bk   = (const float*)d_in[6];
    const float* Wv   = (const float*)d_in[7];
    const float* bv   = (const float*)d_in[8];
    const float* Wsk  = (const float*)d_in[9];
    const float* bsk  = (const float*)d_in[10];
    const float* fcW  = (const float*)d_in[11];
    const float* fcb  = (const float*)d_in[12];
    float* out = (float*)d_out;

    const long NH = (long)N_NODES * HC;   // 6.4M floats
    float* ws   = (float*)d_ws;
    float* q    = ws;                    // NH
    float* k    = q + NH;                // NH
    float* v    = k + NH;                // NH
    float* skip = v + NH;                // NH
    float* xA   = skip + NH;             // NH
    float* p    = xA + NH;               // E*4
    float* gsum = p + (long)N_EDGES * 4; // G*HC
    float* gcnt = gsum + NGRAPH * HC;    // G
    int*   iws  = (int*)(gcnt + NGRAPH);
    int*   rowptr = iws;                 // N+1
    int*   cnt    = rowptr + (N_NODES + 1);  // N (reused as fill)
    int*   esrc   = cnt + N_NODES;       // E
    int*   edst   = esrc + N_EDGES;      // E

    const int gemmGrid = (N_NODES + 63) / 64;                     // 782
    const int eGrid    = (N_EDGES + 255) / 256;                   // 6250
    const int logitGrid = (int)(((long)N_EDGES * 4 + 255) / 256); // 25000 (16 edges/wave)
    const int nodeGrid = (N_NODES + 3) / 4;                       // 12500 (4 waves/block)

    // ---- CSR build (once per launch; edge_index is layer-invariant) ----
    zero_i32<<<256, 256, 0, stream>>>(cnt, N_NODES);
    hist_dst<<<eGrid, 256, 0, stream>>>(ei, cnt);
    scan_rowptr<<<1, SCAN_T, 0, stream>>>(cnt, rowptr);
    zero_i32<<<256, 256, 0, stream>>>(cnt, N_NODES);   // reuse as fill
    scatter_edges<<<eGrid, 256, 0, stream>>>(ei, rowptr, cnt, esrc, edst);

    // ---- layers ----
    const float* xin = x0;
    for (int l = 0; l < LAYERS; ++l) {
        const long wOff = (long)l * HC * HC;
        const long bOff = (long)l * HC;
        gemm4<<<gemmGrid, 256, 0, stream>>>(xin,
            Wq + wOff, bq + bOff, Wk + wOff, bk + bOff,
            Wv + wOff, bv + bOff, Wsk + wOff, bsk + bOff,
            q, k, v, skip);
        edge_logits_sorted<<<logitGrid, 256, 0, stream>>>(q, k, esrc, edst, p);
        node_aggregate<<<nodeGrid, 256, 0, stream>>>(v, p, skip, rowptr, esrc, xA);
        xin = xA;
    }

    // ---- pooling + fc ----
    zero_f32<<<64, 256, 0, stream>>>(gsum, (long)NGRAPH * HC + NGRAPH);
    pool_sum2<<<(N_NODES + POOL_CHUNK - 1) / POOL_CHUNK, 128, 0, stream>>>(xin, batch, gsum, gcnt);
    final_fc<<<(NGRAPH * OUT_CH + 255) / 256, 256, 0, stream>>>(gsum, gcnt, fcW, fcb, out);
}

// Round 6
// 1470.385 us; speedup vs baseline: 1.5515x; 1.2887x over previous
//
#include <hip/hip_runtime.h>

#define N_NODES 50000
#define N_EDGES 1600000
#define HC 128        // H*C == IN
#define LAYERS 3
#define NGRAPH 64
#define OUT_CH 64

// ---------------- zero helpers ----------------
__global__ void zero_f32(float* __restrict__ p, long n) {
    long i = (long)blockIdx.x * blockDim.x + threadIdx.x;
    long stride = (long)gridDim.x * blockDim.x;
    for (; i < n; i += stride) p[i] = 0.f;
}
__global__ void zero_i32(int* __restrict__ p, int n) {
    int i = blockIdx.x * blockDim.x + threadIdx.x;
    int stride = gridDim.x * blockDim.x;
    for (; i < n; i += stride) p[i] = 0;
}

// ---------------- CSR build: histogram -> scan -> scatter ----------------
__global__ void hist_dst(const int* __restrict__ ei, int* __restrict__ cnt) {
    int e = blockIdx.x * blockDim.x + threadIdx.x;
    if (e < N_EDGES) atomicAdd(&cnt[ei[N_EDGES + e]], 1);
}

#define SCAN_T 1024
__global__ __launch_bounds__(SCAN_T) void scan_rowptr(
    const int* __restrict__ cnt, int* __restrict__ rowptr)
{
    __shared__ int part[SCAN_T];
    const int t = threadIdx.x;
    const int CHK = (N_NODES + SCAN_T - 1) / SCAN_T;   // 49
    const int base = t * CHK;
    int s = 0;
    for (int i = 0; i < CHK; ++i) {
        int idx = base + i;
        if (idx < N_NODES) s += cnt[idx];
    }
    part[t] = s;
    __syncthreads();
    for (int off = 1; off < SCAN_T; off <<= 1) {
        int add = (t >= off) ? part[t - off] : 0;
        __syncthreads();
        part[t] += add;
        __syncthreads();
    }
    int run = part[t] - s;   // exclusive prefix of this thread's chunk
    for (int i = 0; i < CHK; ++i) {
        int idx = base + i;
        if (idx < N_NODES) {
            rowptr[idx] = run;
            run += cnt[idx];
        }
    }
    if (t == SCAN_T - 1) rowptr[N_NODES] = part[t];
}

__global__ void scatter_edges(const int* __restrict__ ei,
                              const int* __restrict__ rowptr,
                              int* __restrict__ fill,
                              int* __restrict__ esrc)
{
    int e = blockIdx.x * blockDim.x + threadIdx.x;
    if (e < N_EDGES) {
        int d = ei[N_EDGES + e];
        int pos = rowptr[d] + atomicAdd(&fill[d], 1);
        esrc[pos] = ei[e];
    }
}

// ---------------- fused 4-matrix GEMM: 128-row tile, 8x8 register blocking ---
// out layouts: q [N][128] stride 128; kv [N][256] (k in 0..127, v in 128..255);
// skip [N][128]. Thread rows strided by 16 -> LDS reads hit 4 distinct banks.
__global__ __launch_bounds__(256) void gemm4(
    const float* __restrict__ x,
    const float* __restrict__ Wq, const float* __restrict__ bq,
    const float* __restrict__ Wk, const float* __restrict__ bk,
    const float* __restrict__ Wv, const float* __restrict__ bv,
    const float* __restrict__ Wsk, const float* __restrict__ bsk,
    float* __restrict__ oq, float* __restrict__ okv, float* __restrict__ osk)
{
    __shared__ float xs[128][132];   // 67.6 KB; pad 4 floats
    const int bRow = blockIdx.x * 128;
    const int tid = threadIdx.x;

    for (int i = tid; i < 128 * 32; i += 256) {
        int r = i >> 5, c4 = i & 31;
        int gr = bRow + r;
        float4 val = make_float4(0.f, 0.f, 0.f, 0.f);
        if (gr < N_NODES)
            val = *reinterpret_cast<const float4*>(x + (long)gr * HC + c4 * 4);
        *reinterpret_cast<float4*>(&xs[r][c4 * 4]) = val;
    }
    __syncthreads();

    const int rg = tid >> 4;   // 0..15; thread rows rg + 16*i, i=0..7
    const int cg = tid & 15;   // cols cg*8 .. cg*8+7

    const float* Wm[4] = {Wq, Wk, Wv, Wsk};
    const float* bm[4] = {bq, bk, bv, bsk};
    float* ob[4];
    long  os[4];
    ob[0] = oq;       os[0] = HC;
    ob[1] = okv;      os[1] = 2 * HC;
    ob[2] = okv + HC; os[2] = 2 * HC;
    ob[3] = osk;      os[3] = HC;

    #pragma unroll
    for (int m = 0; m < 4; ++m) {
        const float* __restrict__ W = Wm[m];
        const float* __restrict__ b = bm[m];
        float acc[8][8];
        #pragma unroll
        for (int i = 0; i < 8; ++i)
            #pragma unroll
            for (int j = 0; j < 8; ++j) acc[i][j] = b[cg * 8 + j];

        #pragma unroll 2
        for (int kk = 0; kk < 128; ++kk) {
            float4 w0 = *reinterpret_cast<const float4*>(W + kk * HC + cg * 8);
            float4 w1 = *reinterpret_cast<const float4*>(W + kk * HC + cg * 8 + 4);
            float wv[8] = {w0.x, w0.y, w0.z, w0.w, w1.x, w1.y, w1.z, w1.w};
            #pragma unroll
            for (int i = 0; i < 8; ++i) {
                float xv = xs[rg + 16 * i][kk];
                #pragma unroll
                for (int j = 0; j < 8; ++j) acc[i][j] += xv * wv[j];
            }
        }
        float* __restrict__ o = ob[m];
        const long stride = os[m];
        #pragma unroll
        for (int i = 0; i < 8; ++i) {
            int gr = bRow + rg + 16 * i;
            if (gr < N_NODES) {
                float* dst = o + (long)gr * stride + cg * 8;
                *reinterpret_cast<float4*>(dst) =
                    make_float4(acc[i][0], acc[i][1], acc[i][2], acc[i][3]);
                *reinterpret_cast<float4*>(dst + 4) =
                    make_float4(acc[i][4], acc[i][5], acc[i][6], acc[i][7]);
            }
        }
    }
}

// ---------------- fused attention: logits + softmax + aggregate + skip + relu
// One wave per dst node. Lane l owns channels c0=l, c1=l+64.
// Head of c0 = l>>5 (0/1); head of c1 = 2 + (l>>5).
// Per edge: wave gathers the contiguous 1KB kv row of src; 4-head dots via
// 5-step shfl_xor butterfly within 32-lane halves; p=exp(dot*scale);
// acc += p*v. Softmax normalization by running sum (no max-shift: logits are
// O(1), exp-safe; softmax is shift-invariant so result is exact).
__global__ __launch_bounds__(256) void edge_attn(
    const float* __restrict__ q, const float* __restrict__ kv,
    const float* __restrict__ skip,
    const int* __restrict__ rowptr, const int* __restrict__ esrc,
    float* __restrict__ xout)
{
    const int lane = threadIdx.x & 63;
    const int node = (int)(((long)blockIdx.x * blockDim.x + threadIdx.x) >> 6);
    if (node >= N_NODES) return;
    const int beg = rowptr[node], end = rowptr[node + 1];
    const int c0 = lane, c1 = lane + 64;
    const long qb = (long)node * HC;
    const float q0 = q[qb + c0];
    const float q1 = q[qb + c1];
    const float scale = 0.17677669529663687f;  // 1/sqrt(32)

    float acc0 = 0.f, acc1 = 0.f, ps0 = 0.f, ps1 = 0.f;
    int pos = beg;
    // 2-edge unroll: two independent load+reduce chains for ILP
    for (; pos + 2 <= end; pos += 2) {
        const float* ra = kv + (long)esrc[pos] * (2 * HC);
        const float* rb = kv + (long)esrc[pos + 1] * (2 * HC);
        float ka0 = ra[c0], ka1 = ra[c1], va0 = ra[HC + c0], va1 = ra[HC + c1];
        float kb0 = rb[c0], kb1 = rb[c1], vb0 = rb[HC + c0], vb1 = rb[HC + c1];
        float sa0 = q0 * ka0, sa1 = q1 * ka1;
        float sb0 = q0 * kb0, sb1 = q1 * kb1;
        #pragma unroll
        for (int m = 1; m <= 16; m <<= 1) {
            sa0 += __shfl_xor(sa0, m, 64);
            sa1 += __shfl_xor(sa1, m, 64);
            sb0 += __shfl_xor(sb0, m, 64);
            sb1 += __shfl_xor(sb1, m, 64);
        }
        float pa0 = __expf(sa0 * scale), pa1 = __expf(sa1 * scale);
        float pb0 = __expf(sb0 * scale), pb1 = __expf(sb1 * scale);
        acc0 += pa0 * va0 + pb0 * vb0;
        acc1 += pa1 * va1 + pb1 * vb1;
        ps0 += pa0 + pb0;
        ps1 += pa1 + pb1;
    }
    if (pos < end) {
        const float* ra = kv + (long)esrc[pos] * (2 * HC);
        float ka0 = ra[c0], ka1 = ra[c1], va0 = ra[HC + c0], va1 = ra[HC + c1];
        float sa0 = q0 * ka0, sa1 = q1 * ka1;
        #pragma unroll
        for (int m = 1; m <= 16; m <<= 1) {
            sa0 += __shfl_xor(sa0, m, 64);
            sa1 += __shfl_xor(sa1, m, 64);
        }
        float pa0 = __expf(sa0 * scale), pa1 = __expf(sa1 * scale);
        acc0 += pa0 * va0;
        acc1 += pa1 * va1;
        ps0 += pa0;
        ps1 += pa1;
    }
    float r0 = acc0 / (ps0 + 1e-16f) + skip[qb + c0];
    float r1 = acc1 / (ps1 + 1e-16f) + skip[qb + c1];
    xout[qb + c0] = r0 > 0.f ? r0 : 0.f;
    xout[qb + c1] = r1 > 0.f ? r1 : 0.f;
}

// ---------------- global mean pool: chunked run-length reduction ---------
#define POOL_CHUNK 64
__global__ __launch_bounds__(128) void pool_sum2(
    const float* __restrict__ x, const int* __restrict__ batch,
    float* __restrict__ gsum, float* __restrict__ gcnt)
{
    const int c = threadIdx.x;            // 0..127 (channel)
    const int base = blockIdx.x * POOL_CHUNK;
    if (base >= N_NODES) return;
    const int end = min(base + POOL_CHUNK, N_NODES);
    float acc = 0.f;
    int cnt = 0;
    int curg = batch[base];
    for (int n = base; n < end; ++n) {
        int g = batch[n];
        if (g != curg) {
            atomicAdd(&gsum[curg * HC + c], acc);
            if (c == 0) atomicAdd(&gcnt[curg], (float)cnt);
            acc = 0.f; cnt = 0; curg = g;
        }
        acc += x[(long)n * HC + c];
        cnt++;
    }
    atomicAdd(&gsum[curg * HC + c], acc);
    if (c == 0) atomicAdd(&gcnt[curg], (float)cnt);
}

// ---------------- final FC ----------------
__global__ void final_fc(const float* __restrict__ gsum, const float* __restrict__ gcnt,
                         const float* __restrict__ fcW, const float* __restrict__ fcb,
                         float* __restrict__ out)
{
    int i = blockIdx.x * blockDim.x + threadIdx.x;
    if (i < NGRAPH * OUT_CH) {
        int g = i >> 6, o = i & 63;
        float cnt = gcnt[g];
        cnt = cnt > 1.f ? cnt : 1.f;
        float inv = 1.f / cnt;
        float accv = fcb[o];
        for (int c = 0; c < HC; ++c)
            accv += (gsum[g * HC + c] * inv) * fcW[c * OUT_CH + o];
        out[i] = accv;
    }
}

extern "C" void kernel_launch(void* const* d_in, const int* in_sizes, int n_in,
                              void* d_out, int out_size, void* d_ws, size_t ws_size,
                              hipStream_t stream)
{
    const float* x0   = (const float*)d_in[0];
    const int*   ei   = (const int*)d_in[1];
    const int*   batch= (const int*)d_in[2];
    const float* Wq   = (const float*)d_in[3];
    const float* bq   = (const float*)d_in[4];
    const float* Wk   = (const float*)d_in[5];
    const float* bk   = (const float*)d_in[6];
    const float* Wv   = (const float*)d_in[7];
    const float* bv   = (const float*)d_in[8];
    const float* Wsk  = (const float*)d_in[9];
    const float* bsk  = (const float*)d_in[10];
    const float* fcW  = (const float*)d_in[11];
    const float* fcb  = (const float*)d_in[12];
    float* out = (float*)d_out;

    const long NH = (long)N_NODES * HC;   // 6.4M floats
    float* ws   = (float*)d_ws;
    float* q    = ws;                    // NH
    float* kv   = q + NH;                // 2*NH  (k|v interleaved per node)
    float* skip = kv + 2 * NH;           // NH
    float* xA   = skip + NH;             // NH
    float* gsum = xA + NH;               // G*HC
    float* gcnt = gsum + NGRAPH * HC;    // G
    int*   iws  = (int*)(gcnt + NGRAPH);
    int*   rowptr = iws;                 // N+1
    int*   cnt    = rowptr + (N_NODES + 1);  // N (reused as fill)
    int*   esrc   = cnt + N_NODES;       // E

    const int gemmGrid = (N_NODES + 127) / 128;                   // 391
    const int eGrid    = (N_EDGES + 255) / 256;                   // 6250
    const int nodeGrid = (N_NODES + 3) / 4;                       // 12500 (4 waves/block)

    // ---- CSR build (edge_index is layer-invariant) ----
    zero_i32<<<256, 256, 0, stream>>>(cnt, N_NODES);
    hist_dst<<<eGrid, 256, 0, stream>>>(ei, cnt);
    scan_rowptr<<<1, SCAN_T, 0, stream>>>(cnt, rowptr);
    zero_i32<<<256, 256, 0, stream>>>(cnt, N_NODES);   // reuse as fill
    scatter_edges<<<eGrid, 256, 0, stream>>>(ei, rowptr, cnt, esrc);

    // ---- layers ----
    const float* xin = x0;
    for (int l = 0; l < LAYERS; ++l) {
        const long wOff = (long)l * HC * HC;
        const long bOff = (long)l * HC;
        gemm4<<<gemmGrid, 256, 0, stream>>>(xin,
            Wq + wOff, bq + bOff, Wk + wOff, bk + bOff,
            Wv + wOff, bv + bOff, Wsk + wOff, bsk + bOff,
            q, kv, skip);
        edge_attn<<<nodeGrid, 256, 0, stream>>>(q, kv, skip, rowptr, esrc, xA);
        xin = xA;
    }

    // ---- pooling + fc ----
    zero_f32<<<64, 256, 0, stream>>>(gsum, (long)NGRAPH * HC + NGRAPH);
    pool_sum2<<<(N_NODES + POOL_CHUNK - 1) / POOL_CHUNK, 128, 0, stream>>>(xin, batch, gsum, gcnt);
    final_fc<<<(NGRAPH * OUT_CH + 255) / 256, 256, 0, stream>>>(gsum, gcnt, fcW, fcb, out);
}